// Round 1
// baseline (598.291 us; speedup 1.0000x reference)
//
#include <hip/hip_runtime.h>

// SelfAttention (non-local block), B=4, C=128, H=W=64, N=HW=4096.
// Outputs: [x + relu(bn(conv(attn@g)))] (2,097,152 f32)  ++  attn (67,108,864 f32)
//
// Key layout fact: torch .view(B,-1,C) of a (B,C,H,W) buffer makes the (C,HW)
// conv output buffer literally the (N,C) row-major matrix (flat n*128+c == o*4096+s).
//
// Pipeline:
//  k_prep      : theta/phi/g = bn(relu(conv1x1(x)))  -> fp16, fm layout (== (N,C) row-major)
//  k_tr_g      : gt[c][m] = g[m][c]                  (PV B-fragment wants G^T rows)
//  k_sweep1    : QK^T (fp16 MFMA, f32 acc), per-row online (max, sumexp) -> partial stats
//  k_merge_stat: merge 4 col-chunk partials -> (M, 1/L) per row
//  k_sweep2    : recompute QK^T, P = exp(z-M)/L -> write attn (f32), P->LDS->A-frag,
//                PV MFMA -> partial T per col-chunk (fp16)
//  k_merge_t   : sum 4 partial T -> t (fp16, (N,C) flat == (C,HW) fm)
//  k_outconv   : out0 = x + relu(bn(conv1x1(t)))     (f32 VALU)

typedef _Float16 f16;
typedef __attribute__((ext_vector_type(8))) _Float16 f16x8;
typedef __attribute__((ext_vector_type(4))) float f32x4;

#define CC 128
#define NN 4096
#define BB 4
#define NC (NN * CC)        // 524288 elements per batch
#define EPS_BN 1e-5f

// workspace offsets (bytes); total ~37 MB
#define OFF_THETA  (0ull)
#define OFF_PHI    (4ull << 20)
#define OFF_G      (8ull << 20)
#define OFF_GT     (12ull << 20)
#define OFF_PSTAT  (16ull << 20)                 // [4][B][N] float2 = 512 KB
#define OFF_STAT   (OFF_PSTAT + (1ull << 19))    // [B][N] float2 = 128 KB
#define OFF_TPART  (17ull << 20)                 // [4][B][N][C] f16 = 16 MB
#define OFF_T      (33ull << 20)                 // [B][N][C] f16 = 4 MB

// ---------------------------------------------------------------------------
// K1: fused 1x1 conv + bias + relu + BN for theta/phi/g.  f32 VALU, weights via
// uniform (scalar) loads. Each thread: 8 out-channels x 2 spatial x 3 branches.
__global__ __launch_bounds__(256) void k_prep(
    const float* __restrict__ x,
    const float* __restrict__ t_w, const float* __restrict__ t_b,
    const float* __restrict__ t_ga, const float* __restrict__ t_be,
    const float* __restrict__ t_me, const float* __restrict__ t_va,
    const float* __restrict__ p_w, const float* __restrict__ p_b,
    const float* __restrict__ p_ga, const float* __restrict__ p_be,
    const float* __restrict__ p_me, const float* __restrict__ p_va,
    const float* __restrict__ g_w, const float* __restrict__ g_b,
    const float* __restrict__ g_ga, const float* __restrict__ g_be,
    const float* __restrict__ g_me, const float* __restrict__ g_va,
    f16* __restrict__ th, f16* __restrict__ ph, f16* __restrict__ gh)
{
  const int s0 = blockIdx.x * 512 + threadIdx.x;
  const int s1 = s0 + 256;
  const int o0 = blockIdx.y * 8;
  const int b  = blockIdx.z;
  const float* xb = x + (size_t)b * NC;

  float acc[3][8][2];
#pragma unroll
  for (int br = 0; br < 3; ++br)
#pragma unroll
    for (int j = 0; j < 8; ++j) { acc[br][j][0] = 0.f; acc[br][j][1] = 0.f; }

#pragma unroll 4
  for (int c = 0; c < CC; ++c) {
    float x0 = xb[c * NN + s0];
    float x1 = xb[c * NN + s1];
#pragma unroll
    for (int j = 0; j < 8; ++j) {
      float w0 = t_w[(o0 + j) * CC + c];   // uniform -> s_load
      float w1 = p_w[(o0 + j) * CC + c];
      float w2 = g_w[(o0 + j) * CC + c];
      acc[0][j][0] += w0 * x0; acc[0][j][1] += w0 * x1;
      acc[1][j][0] += w1 * x0; acc[1][j][1] += w1 * x1;
      acc[2][j][0] += w2 * x0; acc[2][j][1] += w2 * x1;
    }
  }

  f16* outs[3] = { th, ph, gh };
  const float* bi[3] = { t_b,  p_b,  g_b  };
  const float* ga[3] = { t_ga, p_ga, g_ga };
  const float* be[3] = { t_be, p_be, g_be };
  const float* me[3] = { t_me, p_me, g_me };
  const float* va[3] = { t_va, p_va, g_va };
#pragma unroll
  for (int br = 0; br < 3; ++br) {
#pragma unroll
    for (int j = 0; j < 8; ++j) {
      int o = o0 + j;
      float inv = ga[br][o] * rsqrtf(va[br][o] + EPS_BN);
      float add = be[br][o] - me[br][o] * inv;
      float bs  = bi[br][o];
      float y0 = fmaxf(acc[br][j][0] + bs, 0.f) * inv + add;
      float y1 = fmaxf(acc[br][j][1] + bs, 0.f) * inv + add;
      f16* op = outs[br] + (size_t)b * NC + (size_t)o * NN;
      op[s0] = (f16)y0;
      op[s1] = (f16)y1;
    }
  }
}

// ---------------------------------------------------------------------------
// K2: transpose g (N=4096 rows, C=128 cols) -> gt (128 rows, 4096 cols), fp16.
__global__ __launch_bounds__(256) void k_tr_g(const f16* __restrict__ gh,
                                              f16* __restrict__ gt)
{
  __shared__ f16 tile[64][72];   // [c2][m], padded stride 144 B (16B-aligned rows)
  const int b   = blockIdx.z;
  const int m0  = blockIdx.x * 64;
  const int c20 = blockIdx.y * 64;
  const f16* gb_ = gh + (size_t)b * NC;
  f16* gtb = gt + (size_t)b * NC;
  const int t = threadIdx.x;
  {
    const int mr = t >> 2, co = (t & 3) * 16;
    f16x8 v0 = *(const f16x8*)(gb_ + (size_t)(m0 + mr) * CC + c20 + co);
    f16x8 v1 = *(const f16x8*)(gb_ + (size_t)(m0 + mr) * CC + c20 + co + 8);
#pragma unroll
    for (int j = 0; j < 8; ++j) tile[co + j][mr] = v0[j];
#pragma unroll
    for (int j = 0; j < 8; ++j) tile[co + 8 + j][mr] = v1[j];
  }
  __syncthreads();
  {
    const int cr = t >> 2, mo = (t & 3) * 16;
    f16x8 w0 = *(const f16x8*)(&tile[cr][mo]);
    f16x8 w1 = *(const f16x8*)(&tile[cr][mo + 8]);
    *(f16x8*)(gtb + (size_t)(c20 + cr) * NN + m0 + mo)     = w0;
    *(f16x8*)(gtb + (size_t)(c20 + cr) * NN + m0 + mo + 8) = w1;
  }
}

// ---------------------------------------------------------------------------
// Sweep kernels: 1 wave per block; wave owns 32 rows x 1024-col chunk.
// grid 2048 = B(4) * chunk(4) * rowblk(128); b = bid&3 -> one batch per XCD
// (bid%8 round-robins XCDs; XCD x sees only b = x&3 -> phi/gt L2-resident).
// MFMA 16x16x32 f16 fragment maps (verified family, learn_hip m89):
//   A: lane l -> A[l&15][(l>>4)*8+e]   B: lane l -> B[(l>>4)*8+e][l&15]
//   D: lane l reg r -> D[(l>>4)*4+r][l&15]
__global__ __launch_bounds__(64, 4) void k_sweep1(
    const f16* __restrict__ th, const f16* __restrict__ ph_,
    float2* __restrict__ pstat)
{
  const int bid = blockIdx.x;
  const int b = bid & 3, chunk = (bid >> 2) & 3, rb = bid >> 4;
  const int lane = threadIdx.x & 63;
  const int lr = lane & 15, lg = lane >> 4;
  const int n0 = rb * 32;
  const f16* tb_ = th  + (size_t)b * NC;
  const f16* pb_ = ph_ + (size_t)b * NC;

  f16x8 a[2][4];
#pragma unroll
  for (int tr = 0; tr < 2; ++tr)
#pragma unroll
    for (int kk = 0; kk < 4; ++kk)
      a[tr][kk] = *(const f16x8*)(tb_ + (size_t)(n0 + tr * 16 + lr) * CC + kk * 32 + lg * 8);

  float mreg[2][4], lreg[2][4];
#pragma unroll
  for (int tr = 0; tr < 2; ++tr)
#pragma unroll
    for (int r = 0; r < 4; ++r) { mreg[tr][r] = -1e30f; lreg[tr][r] = 0.f; }

  const int mbase = chunk * 1024;
  for (int t = 0; t < 64; ++t) {
    const int mc = mbase + t * 16;
    f16x8 bf[4];
#pragma unroll
    for (int kk = 0; kk < 4; ++kk)
      bf[kk] = *(const f16x8*)(pb_ + (size_t)(mc + lr) * CC + kk * 32 + lg * 8);
#pragma unroll
    for (int tr = 0; tr < 2; ++tr) {
      f32x4 d = {0.f, 0.f, 0.f, 0.f};
#pragma unroll
      for (int kk = 0; kk < 4; ++kk)
        d = __builtin_amdgcn_mfma_f32_16x16x32_f16(a[tr][kk], bf[kk], d, 0, 0, 0);
#pragma unroll
      for (int r = 0; r < 4; ++r) {          // per-lane online (max, sumexp)
        float z  = d[r];
        float mn = fmaxf(mreg[tr][r], z);
        lreg[tr][r] = lreg[tr][r] * __expf(mreg[tr][r] - mn) + __expf(z - mn);
        mreg[tr][r] = mn;
      }
    }
  }
  // merge 16 col-subsets of each row (lanes of one 16-group hold the same rows)
#pragma unroll
  for (int off = 1; off < 16; off <<= 1) {
#pragma unroll
    for (int tr = 0; tr < 2; ++tr)
#pragma unroll
      for (int r = 0; r < 4; ++r) {
        float mo = __shfl_xor(mreg[tr][r], off);
        float lo = __shfl_xor(lreg[tr][r], off);
        float mn = fmaxf(mreg[tr][r], mo);
        lreg[tr][r] = lreg[tr][r] * __expf(mreg[tr][r] - mn) + lo * __expf(mo - mn);
        mreg[tr][r] = mn;
      }
  }
  if (lr == 0) {
#pragma unroll
    for (int tr = 0; tr < 2; ++tr)
#pragma unroll
      for (int r = 0; r < 4; ++r) {
        int n = n0 + tr * 16 + lg * 4 + r;
        pstat[(size_t)(chunk * BB + b) * NN + n] = make_float2(mreg[tr][r], lreg[tr][r]);
      }
  }
}

__global__ void k_merge_stats(const float2* __restrict__ pstat,
                              float2* __restrict__ stat)
{
  int i = blockIdx.x * 256 + threadIdx.x;          // 0..16383 = b*N + n
  float2 s0 = pstat[i];
  float2 s1 = pstat[(size_t)BB * NN + i];
  float2 s2 = pstat[(size_t)2 * BB * NN + i];
  float2 s3 = pstat[(size_t)3 * BB * NN + i];
  float m = fmaxf(fmaxf(s0.x, s1.x), fmaxf(s2.x, s3.x));
  float L = s0.y * __expf(s0.x - m) + s1.y * __expf(s1.x - m) +
            s2.y * __expf(s2.x - m) + s3.y * __expf(s3.x - m);
  stat[i] = make_float2(m, 1.0f / L);
}

__global__ __launch_bounds__(64, 2) void k_sweep2(
    const f16* __restrict__ th, const f16* __restrict__ ph_,
    const f16* __restrict__ gt, const float2* __restrict__ stat,
    float* __restrict__ attn, f16* __restrict__ tpart)
{
  __shared__ f16 plds[32 * 40];   // P bounce: 32 rows, stride 40 halfs (80 B)
  const int bid = blockIdx.x;
  const int b = bid & 3, chunk = (bid >> 2) & 3, rb = bid >> 4;
  const int lane = threadIdx.x & 63;
  const int lr = lane & 15, lg = lane >> 4;
  const int n0 = rb * 32;
  const f16* tb_ = th  + (size_t)b * NC;
  const f16* pb_ = ph_ + (size_t)b * NC;
  const f16* gb_ = gt  + (size_t)b * NC;

  f16x8 a[2][4];
#pragma unroll
  for (int tr = 0; tr < 2; ++tr)
#pragma unroll
    for (int kk = 0; kk < 4; ++kk)
      a[tr][kk] = *(const f16x8*)(tb_ + (size_t)(n0 + tr * 16 + lr) * CC + kk * 32 + lg * 8);

  float M[2][4], Li[2][4];
#pragma unroll
  for (int tr = 0; tr < 2; ++tr)
#pragma unroll
    for (int r = 0; r < 4; ++r) {
      float2 st = stat[(size_t)b * NN + n0 + tr * 16 + lg * 4 + r];
      M[tr][r] = st.x; Li[tr][r] = st.y;
    }

  f32x4 tacc[2][8];
#pragma unroll
  for (int tr = 0; tr < 2; ++tr)
#pragma unroll
    for (int ct = 0; ct < 8; ++ct) tacc[tr][ct] = (f32x4){0.f, 0.f, 0.f, 0.f};

  float* attn_b = attn + (size_t)b * NN * NN;
  const int mbase = chunk * 1024;

  for (int grp = 0; grp < 32; ++grp) {
    const int m0 = mbase + grp * 32;
#pragma unroll
    for (int sub = 0; sub < 2; ++sub) {
      const int mc = m0 + sub * 16;
      f16x8 bf[4];
#pragma unroll
      for (int kk = 0; kk < 4; ++kk)
        bf[kk] = *(const f16x8*)(pb_ + (size_t)(mc + lr) * CC + kk * 32 + lg * 8);
#pragma unroll
      for (int tr = 0; tr < 2; ++tr) {
        f32x4 d = {0.f, 0.f, 0.f, 0.f};
#pragma unroll
        for (int kk = 0; kk < 4; ++kk)
          d = __builtin_amdgcn_mfma_f32_16x16x32_f16(a[tr][kk], bf[kk], d, 0, 0, 0);
#pragma unroll
        for (int r = 0; r < 4; ++r) {
          float p = __expf(d[r] - M[tr][r]) * Li[tr][r];   // normalized softmax
          attn_b[(size_t)(n0 + tr * 16 + lg * 4 + r) * NN + mc + lr] = p;
          plds[(tr * 16 + lg * 4 + r) * 40 + sub * 16 + lr] = (f16)p;
        }
      }
    }
    // PV over this 32-col group: A = P (from LDS bounce), B = gt rows (c2)
    f16x8 pa[2];
#pragma unroll
    for (int tr = 0; tr < 2; ++tr)
      pa[tr] = *(const f16x8*)(&plds[(tr * 16 + lr) * 40 + lg * 8]);
#pragma unroll
    for (int ct = 0; ct < 8; ++ct) {
      f16x8 gbf = *(const f16x8*)(gb_ + (size_t)(ct * 16 + lr) * NN + m0 + lg * 8);
#pragma unroll
      for (int tr = 0; tr < 2; ++tr)
        tacc[tr][ct] = __builtin_amdgcn_mfma_f32_16x16x32_f16(pa[tr], gbf, tacc[tr][ct], 0, 0, 0);
    }
  }

  f16* tp = tpart + (size_t)(chunk * BB + b) * NC;
#pragma unroll
  for (int tr = 0; tr < 2; ++tr)
#pragma unroll
    for (int ct = 0; ct < 8; ++ct)
#pragma unroll
      for (int r = 0; r < 4; ++r)
        tp[(size_t)(n0 + tr * 16 + lg * 4 + r) * CC + ct * 16 + lr] = (f16)tacc[tr][ct][r];
}

__global__ void k_merge_t(const f16* __restrict__ tpart, f16* __restrict__ t_h)
{
  int i = blockIdx.x * 256 + threadIdx.x;          // 0..262143, 8 halfs each
  size_t base = (size_t)i * 8;
  f16x8 v0 = *(const f16x8*)(tpart + base);
  f16x8 v1 = *(const f16x8*)(tpart + (size_t)BB * NC + base);
  f16x8 v2 = *(const f16x8*)(tpart + (size_t)2 * BB * NC + base);
  f16x8 v3 = *(const f16x8*)(tpart + (size_t)3 * BB * NC + base);
  f16x8 o;
#pragma unroll
  for (int j = 0; j < 8; ++j)
    o[j] = (f16)((float)v0[j] + (float)v1[j] + (float)v2[j] + (float)v3[j]);
  *(f16x8*)(t_h + base) = o;
}

// ---------------------------------------------------------------------------
// K7: out conv + BN + relu + residual.  t (N,C) flat == t_fm (C,HW) flat.
__global__ __launch_bounds__(256) void k_outconv(
    const float* __restrict__ x, const f16* __restrict__ t_h,
    const float* __restrict__ o_w, const float* __restrict__ o_b,
    const float* __restrict__ o_ga, const float* __restrict__ o_be,
    const float* __restrict__ o_me, const float* __restrict__ o_va,
    float* __restrict__ out0)
{
  const int s0 = blockIdx.x * 512 + threadIdx.x;
  const int s1 = s0 + 256;
  const int o0 = blockIdx.y * 8;
  const int b  = blockIdx.z;
  const f16* tb_ = t_h + (size_t)b * NC;
  float acc[8][2];
#pragma unroll
  for (int j = 0; j < 8; ++j) { acc[j][0] = 0.f; acc[j][1] = 0.f; }

#pragma unroll 4
  for (int c = 0; c < CC; ++c) {
    float t0 = (float)tb_[c * NN + s0];
    float t1 = (float)tb_[c * NN + s1];
#pragma unroll
    for (int j = 0; j < 8; ++j) {
      float w = o_w[(o0 + j) * CC + c];    // uniform -> s_load
      acc[j][0] += w * t0; acc[j][1] += w * t1;
    }
  }
#pragma unroll
  for (int j = 0; j < 8; ++j) {
    int o = o0 + j;
    float inv = o_ga[o] * rsqrtf(o_va[o] + EPS_BN);
    float add = o_be[o] - o_me[o] * inv;
    float y0 = fmaxf((acc[j][0] + o_b[o]) * inv + add, 0.f);   // conv -> bn -> relu
    float y1 = fmaxf((acc[j][1] + o_b[o]) * inv + add, 0.f);
    size_t base = (size_t)(b * CC + o) * NN;
    out0[base + s0] = x[base + s0] + y0;
    out0[base + s1] = x[base + s1] + y1;
  }
}

// ---------------------------------------------------------------------------
extern "C" void kernel_launch(void* const* d_in, const int* in_sizes, int n_in,
                              void* d_out, int out_size, void* d_ws, size_t ws_size,
                              hipStream_t stream)
{
  (void)in_sizes; (void)n_in; (void)out_size; (void)ws_size;
  const float* x    = (const float*)d_in[0];
  const float* t_w  = (const float*)d_in[1];
  const float* t_b  = (const float*)d_in[2];
  const float* t_ga = (const float*)d_in[3];
  const float* t_be = (const float*)d_in[4];
  const float* t_me = (const float*)d_in[5];
  const float* t_va = (const float*)d_in[6];
  const float* p_w  = (const float*)d_in[7];
  const float* p_b  = (const float*)d_in[8];
  const float* p_ga = (const float*)d_in[9];
  const float* p_be = (const float*)d_in[10];
  const float* p_me = (const float*)d_in[11];
  const float* p_va = (const float*)d_in[12];
  const float* g_w  = (const float*)d_in[13];
  const float* g_b  = (const float*)d_in[14];
  const float* g_ga = (const float*)d_in[15];
  const float* g_be = (const float*)d_in[16];
  const float* g_me = (const float*)d_in[17];
  const float* g_va = (const float*)d_in[18];
  const float* o_w  = (const float*)d_in[19];
  const float* o_b  = (const float*)d_in[20];
  const float* o_ga = (const float*)d_in[21];
  const float* o_be = (const float*)d_in[22];
  const float* o_me = (const float*)d_in[23];
  const float* o_va = (const float*)d_in[24];

  char* ws = (char*)d_ws;
  f16*    th    = (f16*)   (ws + OFF_THETA);
  f16*    ph    = (f16*)   (ws + OFF_PHI);
  f16*    gh    = (f16*)   (ws + OFF_G);
  f16*    gt    = (f16*)   (ws + OFF_GT);
  float2* pstat = (float2*)(ws + OFF_PSTAT);
  float2* stat  = (float2*)(ws + OFF_STAT);
  f16*    tpart = (f16*)   (ws + OFF_TPART);
  f16*    t_h   = (f16*)   (ws + OFF_T);

  float* out0 = (float*)d_out;
  float* attn = out0 + (size_t)BB * CC * NN;   // 2,097,152 floats in, attn follows

  k_prep<<<dim3(8, 16, BB), 256, 0, stream>>>(
      x, t_w, t_b, t_ga, t_be, t_me, t_va,
         p_w, p_b, p_ga, p_be, p_me, p_va,
         g_w, g_b, g_ga, g_be, g_me, g_va, th, ph, gh);
  k_tr_g<<<dim3(64, 2, BB), 256, 0, stream>>>(gh, gt);
  k_sweep1<<<2048, 64, 0, stream>>>(th, ph, pstat);
  k_merge_stats<<<64, 256, 0, stream>>>(pstat, stat);
  k_sweep2<<<2048, 64, 0, stream>>>(th, ph, gt, stat, attn, tpart);
  k_merge_t<<<1024, 256, 0, stream>>>(tpart, t_h);
  k_outconv<<<dim3(8, 16, BB), 256, 0, stream>>>(
      x, t_h, o_w, o_b, o_ga, o_be, o_me, o_va, out0);
}